// Round 3
// baseline (171.689 us; speedup 1.0000x reference)
//
#include <hip/hip_runtime.h>
#include <hip/hip_bf16.h>

#define NTOKENS 500000
#define NSAMPLED 8192
#define NHID 256
#define BATCH 8192
#define LROW 8193  // 1 + NSAMPLED
#define OUT_TAIL ((size_t)BATCH * LROW)

typedef short s16x8 __attribute__((ext_vector_type(8)));
typedef float f32x4 __attribute__((ext_vector_type(4)));
typedef unsigned short u16;

// RNE float->bf16
static __device__ __forceinline__ u16 f2bf(float f) {
  unsigned u = __float_as_uint(f);
  return (u16)((u + 0x7fffu + ((u >> 16) & 1u)) >> 16);
}

static __device__ __forceinline__ s16x8 pack8(float4 v0, float4 v1) {
  s16x8 o;
  o[0] = (short)f2bf(v0.x); o[1] = (short)f2bf(v0.y);
  o[2] = (short)f2bf(v0.z); o[3] = (short)f2bf(v0.w);
  o[4] = (short)f2bf(v1.x); o[5] = (short)f2bf(v1.y);
  o[6] = (short)f2bf(v1.z); o[7] = (short)f2bf(v1.w);
  return o;
}

static __device__ __forceinline__ void gload_lds16(const void* g, void* l) {
  __builtin_amdgcn_global_load_lds(
      (const __attribute__((address_space(1))) void*)g,
      (__attribute__((address_space(3))) void*)l, 16, 0, 0);
}

// ---- fused prep: [0,1024) A->bf16 | [1024,2048) gather B->bf16 + colconst
//                  | [2048,4096) true logits + zero targets ----
__global__ void k_prep(const float* __restrict__ inputs, const int* __restrict__ labels,
                       const int* __restrict__ sample_ids, const float* __restrict__ tfreq,
                       const float* __restrict__ sfreq, const float* __restrict__ weight,
                       const float* __restrict__ bias, u16* __restrict__ outA,
                       u16* __restrict__ outB, float* __restrict__ colconst,
                       float* __restrict__ out) {
  int bid = blockIdx.x;
  int t = threadIdx.x;
  if (bid < 1024) {                       // inputs fp32 -> bf16 [BATCH][NHID]
    size_t idx = ((size_t)bid * 256 + t) * 8;
    const float4* p = (const float4*)(inputs + idx);
    *(s16x8*)(outA + idx) = pack8(p[0], p[1]);
  } else if (bid < 2048) {                // gather weight[sample_ids] -> bf16; colconst
    int r = (bid - 1024) * 8 + (t >> 5);
    int l = t & 31;
    int s = sample_ids[r];
    const float* src = weight + (size_t)s * NHID + l * 8;
    *(s16x8*)(outB + (size_t)r * NHID + l * 8) =
        pack8(((const float4*)src)[0], ((const float4*)src)[1]);
    if (l == 0) colconst[r] = bias[s] - sfreq[r];
  } else {                                // true logits (col 0) + int32 zeros tail
    int bb = bid - 2048;
    int w = t >> 6, lane = t & 63;
    int b = bb * 4 + w;
    int lab = labels[b];
    const float4 x = *(const float4*)(inputs + (size_t)b * NHID + lane * 4);
    const float4 ww = *(const float4*)(weight + (size_t)lab * NHID + lane * 4);
    float s = x.x * ww.x + x.y * ww.y + x.z * ww.z + x.w * ww.w;
    #pragma unroll
    for (int off = 32; off; off >>= 1) s += __shfl_down(s, off, 64);
    if (lane == 0) out[(size_t)b * LROW] = s + bias[lab] - tfreq[b];
    int tid = bb * 256 + t;
    if (tid < BATCH) out[OUT_TAIL + tid] = 0.0f;
  }
}

// ---- GEMM: C[b][s] = sum_k A[b][k]*B[s][k] + colconst[s] ----
// 128x128 tile, BK=64 x4, single-buffered 32KB LDS, 4 blocks/CU.
// Epilogue stores are NON-TEMPORAL: the 268MB output stream must not
// write-allocate in L2/L3, else it evicts the A/B panels and every block
// re-fetches ~128KB from HBM (the round-2 ~30us gap).
__global__ __launch_bounds__(256, 4) void k_gemm(const u16* __restrict__ A,
                                                 const u16* __restrict__ B,
                                                 const float* __restrict__ colconst,
                                                 float* __restrict__ out) {
  __shared__ u16 lA[128 * 64];
  __shared__ u16 lB[128 * 64];
  int t = threadIdx.x;
  int lane = t & 63;
  int w = t >> 6;
  // XCD rectangle swizzle: xcd = bid&7 gets a 32x16 (brow x bcol) rectangle.
  int bid = blockIdx.x;
  int xcd = bid & 7, idx = bid >> 3;
  int brow = (xcd >> 2) * 32 + (idx >> 4);
  int bcol = (xcd & 3) * 16 + (idx & 15);
  int wr = w >> 1, wc = w & 1;
  const int l15 = lane & 15;
  const int lhi = lane >> 4;

  f32x4 acc[4][4];
  #pragma unroll
  for (int i = 0; i < 4; ++i)
    #pragma unroll
    for (int j = 0; j < 4; ++j) acc[i][j] = (f32x4){0.f, 0.f, 0.f, 0.f};

  const u16* Abase = A + (size_t)brow * 128 * NHID;
  const u16* Bbase = B + (size_t)bcol * 128 * NHID;

  for (int kt = 0; kt < 4; ++kt) {
    #pragma unroll
    for (int i = 0; i < 4; ++i) {
      int chunk = (w * 4 + i) * 64 + lane;  // 0..1023 16B-chunks per tile
      int row = chunk >> 3;                 // 8 chunks per 64-elem row
      int cs = (chunk & 7) ^ (row & 7);     // pre-swizzled source chunk
      const u16* ga = Abase + (size_t)row * NHID + kt * 64 + cs * 8;
      const u16* gb = Bbase + (size_t)row * NHID + kt * 64 + cs * 8;
      gload_lds16(ga, lA + (w * 4 + i) * 512);
      gload_lds16(gb, lB + (w * 4 + i) * 512);
    }
    __syncthreads();
    #pragma unroll
    for (int ks = 0; ks < 2; ++ks) {
      int kc = ks * 4 + lhi;
      s16x8 af[4], bfr[4];
      #pragma unroll
      for (int mi = 0; mi < 4; ++mi) {
        int row = wr * 64 + mi * 16 + l15;
        af[mi] = *(const s16x8*)(lA + row * 64 + ((kc ^ (row & 7)) * 8));
      }
      #pragma unroll
      for (int ni = 0; ni < 4; ++ni) {
        int row = wc * 64 + ni * 16 + l15;
        bfr[ni] = *(const s16x8*)(lB + row * 64 + ((kc ^ (row & 7)) * 8));
      }
      #pragma unroll
      for (int mi = 0; mi < 4; ++mi)
        #pragma unroll
        for (int ni = 0; ni < 4; ++ni)
          acc[mi][ni] = __builtin_amdgcn_mfma_f32_16x16x32_bf16(af[mi], bfr[ni], acc[mi][ni], 0, 0, 0);
    }
    __syncthreads();
  }

  // epilogue: + colconst, NON-TEMPORAL dword stores into stride-8193 rows
  int grow0 = brow * 128 + wr * 64;
  int gcol0 = bcol * 128 + wc * 64;
  float cc[4];
  #pragma unroll
  for (int ni = 0; ni < 4; ++ni) cc[ni] = colconst[gcol0 + ni * 16 + l15];
  #pragma unroll
  for (int mi = 0; mi < 4; ++mi) {
    #pragma unroll
    for (int r = 0; r < 4; ++r) {
      size_t rbase = (size_t)(grow0 + mi * 16 + lhi * 4 + r) * LROW + 1;
      #pragma unroll
      for (int ni = 0; ni < 4; ++ni)
        __builtin_nontemporal_store(acc[mi][ni][r] + cc[ni],
                                    out + rbase + gcol0 + ni * 16 + l15);
    }
  }
}

extern "C" void kernel_launch(void* const* d_in, const int* in_sizes, int n_in,
                              void* d_out, int out_size, void* d_ws, size_t ws_size,
                              hipStream_t stream) {
  const float* inputs          = (const float*)d_in[0];
  const int*   labels          = (const int*)d_in[1];
  const int*   sample_ids      = (const int*)d_in[2];
  const float* true_log_freq   = (const float*)d_in[3];
  const float* sample_log_freq = (const float*)d_in[4];
  const float* weight          = (const float*)d_in[5];
  const float* bias            = (const float*)d_in[6];
  float* out = (float*)d_out;

  u16* wsA = (u16*)d_ws;                                      // 4 MB
  u16* wsB = wsA + (size_t)BATCH * NHID;                      // 4 MB
  float* colconst = (float*)(wsB + (size_t)NSAMPLED * NHID);  // 32 KB

  hipLaunchKernelGGL(k_prep, dim3(4096), dim3(256), 0, stream,
                     inputs, labels, sample_ids, true_log_freq, sample_log_freq,
                     weight, bias, wsA, wsB, colconst, out);
  hipLaunchKernelGGL(k_gemm, dim3(64 * 64), dim3(256), 0, stream, wsA, wsB, colconst, out);
}

// Round 4
// 136.975 us; speedup vs baseline: 1.2534x; 1.2534x over previous
//
#include <hip/hip_runtime.h>
#include <hip/hip_bf16.h>

#define NTOKENS 500000
#define NSAMPLED 8192
#define NHID 256
#define BATCH 8192
#define LROW 8193  // 1 + NSAMPLED
#define OUT_TAIL ((size_t)BATCH * LROW)

typedef short s16x8 __attribute__((ext_vector_type(8)));
typedef float f32x4 __attribute__((ext_vector_type(4)));
typedef unsigned short u16;

// RNE float->bf16
static __device__ __forceinline__ u16 f2bf(float f) {
  unsigned u = __float_as_uint(f);
  return (u16)((u + 0x7fffu + ((u >> 16) & 1u)) >> 16);
}

static __device__ __forceinline__ s16x8 pack8(float4 v0, float4 v1) {
  s16x8 o;
  o[0] = (short)f2bf(v0.x); o[1] = (short)f2bf(v0.y);
  o[2] = (short)f2bf(v0.z); o[3] = (short)f2bf(v0.w);
  o[4] = (short)f2bf(v1.x); o[5] = (short)f2bf(v1.y);
  o[6] = (short)f2bf(v1.z); o[7] = (short)f2bf(v1.w);
  return o;
}

static __device__ __forceinline__ void gload_lds16(const void* g, void* l) {
  __builtin_amdgcn_global_load_lds(
      (const __attribute__((address_space(1))) void*)g,
      (__attribute__((address_space(3))) void*)l, 16, 0, 0);
}

// ---- fused prep: [0,1024) A->bf16 | [1024,2048) gather B->bf16 + colconst
//                  | [2048,4096) true logits + zero targets ----
__global__ void k_prep(const float* __restrict__ inputs, const int* __restrict__ labels,
                       const int* __restrict__ sample_ids, const float* __restrict__ tfreq,
                       const float* __restrict__ sfreq, const float* __restrict__ weight,
                       const float* __restrict__ bias, u16* __restrict__ outA,
                       u16* __restrict__ outB, float* __restrict__ colconst,
                       float* __restrict__ out) {
  int bid = blockIdx.x;
  int t = threadIdx.x;
  if (bid < 1024) {                       // inputs fp32 -> bf16 [BATCH][NHID]
    size_t idx = ((size_t)bid * 256 + t) * 8;
    const float4* p = (const float4*)(inputs + idx);
    *(s16x8*)(outA + idx) = pack8(p[0], p[1]);
  } else if (bid < 2048) {                // gather weight[sample_ids] -> bf16; colconst
    int r = (bid - 1024) * 8 + (t >> 5);
    int l = t & 31;
    int s = sample_ids[r];
    const float* src = weight + (size_t)s * NHID + l * 8;
    *(s16x8*)(outB + (size_t)r * NHID + l * 8) =
        pack8(((const float4*)src)[0], ((const float4*)src)[1]);
    if (l == 0) colconst[r] = bias[s] - sfreq[r];
  } else {                                // true logits (col 0) + int32 zeros tail
    int bb = bid - 2048;
    int w = t >> 6, lane = t & 63;
    int b = bb * 4 + w;
    int lab = labels[b];
    const float4 x = *(const float4*)(inputs + (size_t)b * NHID + lane * 4);
    const float4 ww = *(const float4*)(weight + (size_t)lab * NHID + lane * 4);
    float s = x.x * ww.x + x.y * ww.y + x.z * ww.z + x.w * ww.w;
    #pragma unroll
    for (int off = 32; off; off >>= 1) s += __shfl_down(s, off, 64);
    if (lane == 0) out[(size_t)b * LROW] = s + bias[lab] - tfreq[b];
    int tid = bb * 256 + t;
    if (tid < BATCH) out[OUT_TAIL + tid] = 0.0f;
  }
}

// ---- GEMM: C[b][s] = sum_k A[b][k]*B[s][k] + colconst[s] ----
// Persistent-ish: 1024 blocks (exactly 4/CU), each block keeps one brow and
// loops 4 column tiles (ct). Stores of tile ct overlap the staging of tile
// ct+1 (epilogue touches only registers; LDS is free to restage). 128x128
// tile, BK=64 x4, single-buffered 32KB LDS. Plain dword stores (NT stores
// bypass L2 write-combining: round-3 regression 93->172us).
__global__ __launch_bounds__(256, 4) void k_gemm(const u16* __restrict__ A,
                                                 const u16* __restrict__ B,
                                                 const float* __restrict__ colconst,
                                                 float* __restrict__ out) {
  __shared__ u16 lA[128 * 64];
  __shared__ u16 lB[128 * 64];
  int t = threadIdx.x;
  int lane = t & 63;
  int w = t >> 6;
  // XCD 2D rectangle: xcd = bid&7 (round-robin dispatch). Per XCD: 32 brows x
  // 4 col-slabs -> A panel 2MB + B panel 1MB < 4MiB L2.
  int bid = blockIdx.x;
  int xcd = bid & 7, i = bid >> 3;                // i in 0..127
  int brow = (xcd >> 2) * 32 + (i >> 2);          // 0..63
  int slab = (xcd & 3) * 4 + (i & 3);             // 0..15 (512-col slabs)
  int wr = w >> 1, wc = w & 1;
  const int l15 = lane & 15;
  const int lhi = lane >> 4;

  const u16* Abase = A + (size_t)brow * 128 * NHID;

  for (int ct = 0; ct < 4; ++ct) {
    int bcol = slab * 4 + ct;                     // 0..63
    const u16* Bbase = B + (size_t)bcol * 128 * NHID;

    f32x4 acc[4][4];
    #pragma unroll
    for (int a = 0; a < 4; ++a)
      #pragma unroll
      for (int b = 0; b < 4; ++b) acc[a][b] = (f32x4){0.f, 0.f, 0.f, 0.f};

    for (int kt = 0; kt < 4; ++kt) {
      #pragma unroll
      for (int ii = 0; ii < 4; ++ii) {
        int chunk = (w * 4 + ii) * 64 + lane;     // 0..1023 16B-chunks per tile
        int row = chunk >> 3;                     // 8 chunks per 64-elem row
        int cs = (chunk & 7) ^ (row & 7);         // pre-swizzled source chunk
        gload_lds16(Abase + (size_t)row * NHID + kt * 64 + cs * 8, lA + (w * 4 + ii) * 512);
        gload_lds16(Bbase + (size_t)row * NHID + kt * 64 + cs * 8, lB + (w * 4 + ii) * 512);
      }
      __syncthreads();
      #pragma unroll
      for (int ks = 0; ks < 2; ++ks) {
        int kc = ks * 4 + lhi;
        s16x8 af[4], bfr[4];
        #pragma unroll
        for (int mi = 0; mi < 4; ++mi) {
          int row = wr * 64 + mi * 16 + l15;
          af[mi] = *(const s16x8*)(lA + row * 64 + ((kc ^ (row & 7)) * 8));
        }
        #pragma unroll
        for (int ni = 0; ni < 4; ++ni) {
          int row = wc * 64 + ni * 16 + l15;
          bfr[ni] = *(const s16x8*)(lB + row * 64 + ((kc ^ (row & 7)) * 8));
        }
        #pragma unroll
        for (int mi = 0; mi < 4; ++mi)
          #pragma unroll
          for (int ni = 0; ni < 4; ++ni)
            acc[mi][ni] = __builtin_amdgcn_mfma_f32_16x16x32_bf16(af[mi], bfr[ni], acc[mi][ni], 0, 0, 0);
      }
      __syncthreads();
    }

    // epilogue: + colconst, plain dword stores into stride-8193 rows.
    // Registers only -> next ct's staging may overwrite LDS concurrently.
    int grow0 = brow * 128 + wr * 64;
    int gcol0 = bcol * 128 + wc * 64;
    float cc[4];
    #pragma unroll
    for (int ni = 0; ni < 4; ++ni) cc[ni] = colconst[gcol0 + ni * 16 + l15];
    #pragma unroll
    for (int mi = 0; mi < 4; ++mi) {
      #pragma unroll
      for (int r = 0; r < 4; ++r) {
        size_t rbase = (size_t)(grow0 + mi * 16 + lhi * 4 + r) * LROW + 1;
        #pragma unroll
        for (int ni = 0; ni < 4; ++ni)
          out[rbase + gcol0 + ni * 16 + l15] = acc[mi][ni][r] + cc[ni];
      }
    }
  }
}

extern "C" void kernel_launch(void* const* d_in, const int* in_sizes, int n_in,
                              void* d_out, int out_size, void* d_ws, size_t ws_size,
                              hipStream_t stream) {
  const float* inputs          = (const float*)d_in[0];
  const int*   labels          = (const int*)d_in[1];
  const int*   sample_ids      = (const int*)d_in[2];
  const float* true_log_freq   = (const float*)d_in[3];
  const float* sample_log_freq = (const float*)d_in[4];
  const float* weight          = (const float*)d_in[5];
  const float* bias            = (const float*)d_in[6];
  float* out = (float*)d_out;

  u16* wsA = (u16*)d_ws;                                      // 4 MB
  u16* wsB = wsA + (size_t)BATCH * NHID;                      // 4 MB
  float* colconst = (float*)(wsB + (size_t)NSAMPLED * NHID);  // 32 KB

  hipLaunchKernelGGL(k_prep, dim3(4096), dim3(256), 0, stream,
                     inputs, labels, sample_ids, true_log_freq, sample_log_freq,
                     weight, bias, wsA, wsB, colconst, out);
  hipLaunchKernelGGL(k_gemm, dim3(1024), dim3(256), 0, stream, wsA, wsB, colconst, out);
}

// Round 5
// 85.558 us; speedup vs baseline: 2.0067x; 1.6010x over previous
//
#include <hip/hip_runtime.h>
#include <hip/hip_bf16.h>

#define NTOKENS 500000
#define NSAMPLED 8192
#define NHID 256
#define BATCH 8192
#define LROW 8193  // 1 + NSAMPLED
#define OUT_TAIL ((size_t)BATCH * LROW)

typedef short s16x8 __attribute__((ext_vector_type(8)));
typedef float f32x4 __attribute__((ext_vector_type(4)));
typedef unsigned short u16;

// RNE float->bf16
static __device__ __forceinline__ u16 f2bf(float f) {
  unsigned u = __float_as_uint(f);
  return (u16)((u + 0x7fffu + ((u >> 16) & 1u)) >> 16);
}

static __device__ __forceinline__ s16x8 pack8(float4 v0, float4 v1) {
  s16x8 o;
  o[0] = (short)f2bf(v0.x); o[1] = (short)f2bf(v0.y);
  o[2] = (short)f2bf(v0.z); o[3] = (short)f2bf(v0.w);
  o[4] = (short)f2bf(v1.x); o[5] = (short)f2bf(v1.y);
  o[6] = (short)f2bf(v1.z); o[7] = (short)f2bf(v1.w);
  return o;
}

static __device__ __forceinline__ void gload_lds16(const void* g, void* l) {
  __builtin_amdgcn_global_load_lds(
      (const __attribute__((address_space(1))) void*)g,
      (__attribute__((address_space(3))) void*)l, 16, 0, 0);
}

// ---- fused prep: [0,1024) A->bf16 | [1024,2048) gather B->bf16 + colconst
//                  | [2048,4096) true logits + zero targets ----
__global__ void k_prep(const float* __restrict__ inputs, const int* __restrict__ labels,
                       const int* __restrict__ sample_ids, const float* __restrict__ tfreq,
                       const float* __restrict__ sfreq, const float* __restrict__ weight,
                       const float* __restrict__ bias, u16* __restrict__ outA,
                       u16* __restrict__ outB, float* __restrict__ colconst,
                       float* __restrict__ out) {
  int bid = blockIdx.x;
  int t = threadIdx.x;
  if (bid < 1024) {                       // inputs fp32 -> bf16 [BATCH][NHID]
    size_t idx = ((size_t)bid * 256 + t) * 8;
    const float4* p = (const float4*)(inputs + idx);
    *(s16x8*)(outA + idx) = pack8(p[0], p[1]);
  } else if (bid < 2048) {                // gather weight[sample_ids] -> bf16; colconst
    int r = (bid - 1024) * 8 + (t >> 5);
    int l = t & 31;
    int s = sample_ids[r];
    const float* src = weight + (size_t)s * NHID + l * 8;
    *(s16x8*)(outB + (size_t)r * NHID + l * 8) =
        pack8(((const float4*)src)[0], ((const float4*)src)[1]);
    if (l == 0) colconst[r] = bias[s] - sfreq[r];
  } else {                                // true logits (col 0) + int32 zeros tail
    int bb = bid - 2048;
    int w = t >> 6, lane = t & 63;
    int b = bb * 4 + w;
    int lab = labels[b];
    const float4 x = *(const float4*)(inputs + (size_t)b * NHID + lane * 4);
    const float4 ww = *(const float4*)(weight + (size_t)lab * NHID + lane * 4);
    float s = x.x * ww.x + x.y * ww.y + x.z * ww.z + x.w * ww.w;
    #pragma unroll
    for (int off = 32; off; off >>= 1) s += __shfl_down(s, off, 64);
    if (lane == 0) out[(size_t)b * LROW] = s + bias[lab] - tfreq[b];
    int tid = bb * 256 + t;
    if (tid < BATCH) out[OUT_TAIL + tid] = 0.0f;
  }
}

// ---- GEMM: C[b][s] = sum_k A[b][k]*B[s][k] + colconst[s] ----
// 128x256 tile (WIDER row segments: 1KB/row vs 512B -> halves partial-line
// and DRAM-page-activate overhead of the odd-stride-8193 output), 512 thr =
// 8 waves of 32x128. BK=64 x4, single-buffered 48KB LDS, 2 blocks/CU
// (16 waves/CU, same as round-2). Plain dword stores (NT regressed r3).
__global__ __launch_bounds__(512, 4) void k_gemm(const u16* __restrict__ A,
                                                 const u16* __restrict__ B,
                                                 const float* __restrict__ colconst,
                                                 float* __restrict__ out) {
  __shared__ u16 lA[128 * 64];  // [row 0..127][k 0..63], XOR-swizzled chunks
  __shared__ u16 lB[256 * 64];  // [col 0..255][k 0..63]
  int t = threadIdx.x;
  int lane = t & 63;
  int w = t >> 6;               // 0..7
  // XCD rectangle: grid 64 rowtiles x 32 coltiles; per XCD 16x16 rectangle
  // -> A 1MB + B 2MB < 4MiB L2. bid&7 = XCD (round-robin dispatch heuristic).
  int bid = blockIdx.x;
  int xcd = bid & 7, i = bid >> 3;        // i in 0..255
  int brow = (xcd >> 1) * 16 + (i >> 4);  // 0..63 (128-row tiles)
  int bcol = (xcd & 1) * 16 + (i & 15);   // 0..31 (256-col tiles)
  int wr = w >> 1, wc = w & 1;            // wave: rows wr*32+, cols wc*128+
  const int l15 = lane & 15;
  const int lhi = lane >> 4;

  f32x4 acc[2][8];
  #pragma unroll
  for (int a = 0; a < 2; ++a)
    #pragma unroll
    for (int b = 0; b < 8; ++b) acc[a][b] = (f32x4){0.f, 0.f, 0.f, 0.f};

  const u16* Abase = A + (size_t)brow * 128 * NHID;
  const u16* Bbase = B + (size_t)bcol * 256 * NHID;

  for (int kt = 0; kt < 4; ++kt) {
    // stage A (1024 chunks) + B (2048 chunks); chunk = 16B. Wave-uniform LDS
    // dest (linear), XOR-pre-swizzled global source (rule #21).
    #pragma unroll
    for (int j = 0; j < 2; ++j) {
      int chunk = w * 128 + j * 64 + lane;
      int row = chunk >> 3;
      int cs = (chunk & 7) ^ (row & 7);
      gload_lds16(Abase + (size_t)row * NHID + kt * 64 + cs * 8,
                  lA + (size_t)(w * 128 + j * 64) * 8);
    }
    #pragma unroll
    for (int j = 0; j < 4; ++j) {
      int chunk = w * 256 + j * 64 + lane;
      int row = chunk >> 3;
      int cs = (chunk & 7) ^ (row & 7);
      gload_lds16(Bbase + (size_t)row * NHID + kt * 64 + cs * 8,
                  lB + (size_t)(w * 256 + j * 64) * 8);
    }
    __syncthreads();
    #pragma unroll
    for (int ks = 0; ks < 2; ++ks) {
      int kc = ks * 4 + lhi;  // 16B-chunk index along the 64-elem K row
      s16x8 af[2];
      #pragma unroll
      for (int mi = 0; mi < 2; ++mi) {
        int row = wr * 32 + mi * 16 + l15;
        af[mi] = *(const s16x8*)(lA + row * 64 + ((kc ^ (row & 7)) * 8));
      }
      #pragma unroll
      for (int ni = 0; ni < 8; ++ni) {
        int row = wc * 128 + ni * 16 + l15;
        s16x8 bf = *(const s16x8*)(lB + row * 64 + ((kc ^ (row & 7)) * 8));
        #pragma unroll
        for (int mi = 0; mi < 2; ++mi)
          acc[mi][ni] = __builtin_amdgcn_mfma_f32_16x16x32_bf16(af[mi], bf, acc[mi][ni], 0, 0, 0);
      }
    }
    __syncthreads();
  }

  // epilogue: + colconst, plain dword stores. Per (mi,r): 8 consecutive 64B
  // segments -> 512B/row per wave-half, 1KB/row per block (row-major sweep).
  int grow0 = brow * 128 + wr * 32;
  int gcol0 = bcol * 256 + wc * 128;
  float cc[8];
  #pragma unroll
  for (int ni = 0; ni < 8; ++ni) cc[ni] = colconst[gcol0 + ni * 16 + l15];
  #pragma unroll
  for (int mi = 0; mi < 2; ++mi) {
    #pragma unroll
    for (int r = 0; r < 4; ++r) {
      size_t rbase = (size_t)(grow0 + mi * 16 + lhi * 4 + r) * LROW + 1;
      #pragma unroll
      for (int ni = 0; ni < 8; ++ni)
        out[rbase + gcol0 + ni * 16 + l15] = acc[mi][ni][r] + cc[ni];
    }
  }
}

extern "C" void kernel_launch(void* const* d_in, const int* in_sizes, int n_in,
                              void* d_out, int out_size, void* d_ws, size_t ws_size,
                              hipStream_t stream) {
  const float* inputs          = (const float*)d_in[0];
  const int*   labels          = (const int*)d_in[1];
  const int*   sample_ids      = (const int*)d_in[2];
  const float* true_log_freq   = (const float*)d_in[3];
  const float* sample_log_freq = (const float*)d_in[4];
  const float* weight          = (const float*)d_in[5];
  const float* bias            = (const float*)d_in[6];
  float* out = (float*)d_out;

  u16* wsA = (u16*)d_ws;                                      // 4 MB
  u16* wsB = wsA + (size_t)BATCH * NHID;                      // 4 MB
  float* colconst = (float*)(wsB + (size_t)NSAMPLED * NHID);  // 32 KB

  hipLaunchKernelGGL(k_prep, dim3(4096), dim3(256), 0, stream,
                     inputs, labels, sample_ids, true_log_freq, sample_log_freq,
                     weight, bias, wsA, wsB, colconst, out);
  hipLaunchKernelGGL(k_gemm, dim3(2048), dim3(512), 0, stream, wsA, wsB, colconst, out);
}